// Round 3
// baseline (359.284 us; speedup 1.0000x reference)
//
#include <hip/hip_runtime.h>

// Fused ResidualTokenAdapter: LN -> down(1024->64) -> GELU(erf) -> up(64->1024) -> +x
// x: (8,4096,1024) fp32.
// R3 design: persistent blocks (grid=256, 1024 thr = 16 waves, 1 block/CU).
// ALL weights (256 KB bf16) live in registers, distributed across waves:
//   down: wave (ct=w&3, kt=w>>2) holds dw[ct*16..+16][kt*256..+256] = 8 s16x8/lane
//   up:   wave w holds uw[w*64..+64][0..64]                         = 8 s16x8/lane
// Block loops over 8 tiles of 16 rows; double-buffered LDS xn tile; register
// x prefetch. Inner loop: zero global weight traffic -> pure x/out streaming.

#define HDIM 1024
#define BDIM 64
#define RT   16    // rows per tile (one wave per row for LN stats)
#define NT   8     // tiles per block
#define XPAD 1032  // xn row stride in shorts: 2064 B; 516 dwords %32 = 4 -> even bank spread
#define GPAD 72    // g row stride in shorts: 144 B; 36 dwords %32 = 4 -> even bank spread

using s16x8 = __attribute__((ext_vector_type(8))) short;
using s16x4 = __attribute__((ext_vector_type(4))) short;
using f32x4 = __attribute__((ext_vector_type(4))) float;

__device__ __forceinline__ short f2bf(float f) {
  unsigned u = __builtin_bit_cast(unsigned, f);
  u += 0x7fffu + ((u >> 16) & 1u);          // round-to-nearest-even
  return (short)(u >> 16);
}

// ---- prep: fp32 weights -> bf16 in ws. dwb = ws[0:65536), uwb = ws[65536:131072)
extern "C" __global__ void prep_weights(const float* __restrict__ dw,
                                        const float* __restrict__ uw,
                                        short* __restrict__ wsbf) {
  int tid = blockIdx.x * 256 + threadIdx.x;          // 0..16383
  const float* src = (tid < 8192) ? dw : uw;
  int off = (tid < 8192) ? tid * 8 : (tid - 8192) * 8;
  f32x4 v0 = *(const f32x4*)(src + off);
  f32x4 v1 = *(const f32x4*)(src + off + 4);
  s16x8 o;
#pragma unroll
  for (int k = 0; k < 4; ++k) { o[k] = f2bf(v0[k]); o[k + 4] = f2bf(v1[k]); }
  *(s16x8*)(wsbf + tid * 8) = o;
}

extern "C" __global__ __launch_bounds__(1024, 4)
void adapter_fused(const float* __restrict__ x,
                   const float* __restrict__ nw, const float* __restrict__ nb,
                   const float* __restrict__ db, const float* __restrict__ ub,
                   const short* __restrict__ dwb, const short* __restrict__ uwb,
                   float* __restrict__ out)
{
  __shared__ __align__(16) short xn[2][RT][XPAD];   // 66 KB  (LN'ed x, bf16, dbuf)
  __shared__ float part[4][4][16][16];              // 16 KB  [kt][ct][m][n] down partials
  __shared__ __align__(16) short gbf[RT][GPAD];     // 2.3 KB gelu(h) bf16
  __shared__ float wln[HDIM];                       // 4 KB
  __shared__ float bln[HDIM];                       // 4 KB

  const int t    = threadIdx.x;
  const int w    = t >> 6;      // wave 0..15
  const int lane = t & 63;
  const int q    = lane >> 4;
  const int c    = lane & 15;
  const int ct   = w & 3;       // down col-tile
  const int kt   = w >> 2;      // down K-quarter

  // stage LN params (one coalesced pass)
  wln[t] = nw[t];
  bln[t] = nb[t];

  // ---- preload weight fragments into registers (once per block, from L2) ----
  s16x8 bdw[8];                 // down B-frags: dw[ct*16+c][kt*256 + s*32 + q*8 ..+8]
  {
    const short* p = dwb + (size_t)(ct * 16 + c) * HDIM + kt * 256 + q * 8;
#pragma unroll
    for (int s = 0; s < 8; ++s) bdw[s] = *(const s16x8*)(p + s * 32);
  }
  s16x8 buw[4][2];              // up B-frags: uw[w*64+j*16+c][h*32 + q*8 ..+8]
  float ubr[4];
#pragma unroll
  for (int j = 0; j < 4; ++j) {
    const short* p = uwb + (size_t)(w * 64 + j * 16 + c) * BDIM + q * 8;
    buw[j][0] = *(const s16x8*)(p);
    buw[j][1] = *(const s16x8*)(p + 32);
    ubr[j] = ub[w * 64 + j * 16 + c];
  }
  const float dbr = db[ct * 16 + c];

  const size_t rowbase = (size_t)blockIdx.x * (RT * NT);

  // x tile load: wave w owns row w of the tile; lane holds float4s at i*64+lane
  f32x4 xv[4];
  auto load_tile = [&](int tile) {
    const f32x4* xr = (const f32x4*)(x + (rowbase + tile * RT + w) * HDIM);
#pragma unroll
    for (int i = 0; i < 4; ++i) xv[i] = xr[i * 64 + lane];
  };
  // LN stats (wave-wide) + normalize + bf16 store to xn[buf]
  auto stats_store = [&](int buf) {
    float sum = 0.f, ssq = 0.f;
#pragma unroll
    for (int i = 0; i < 4; ++i)
#pragma unroll
      for (int k = 0; k < 4; ++k) { float f = xv[i][k]; sum += f; ssq += f * f; }
#pragma unroll
    for (int m = 1; m < 64; m <<= 1) {
      sum += __shfl_xor(sum, m);
      ssq += __shfl_xor(ssq, m);
    }
    const float mu  = sum * (1.0f / HDIM);
    const float var = ssq * (1.0f / HDIM) - mu * mu;
    const float rs  = rsqrtf(var + 1e-5f);
#pragma unroll
    for (int i = 0; i < 4; ++i) {
      int j = (i * 64 + lane) * 4;
      f32x4 lw = *(const f32x4*)&wln[j];
      f32x4 lb = *(const f32x4*)&bln[j];
      s16x4 o;
#pragma unroll
      for (int k = 0; k < 4; ++k)
        o[k] = f2bf((xv[i][k] - mu) * rs * lw[k] + lb[k]);
      *(s16x4*)&xn[buf][w][j] = o;
    }
  };

  // prologue
  load_tile(0);
  __syncthreads();              // wln/bln ready
  stats_store(0);
  __syncthreads();              // xn[0] ready

  for (int tile = 0; tile < NT; ++tile) {
    const int cur = tile & 1, nxt = cur ^ 1;
    load_tile(tile + 1 < NT ? tile + 1 : tile);     // issue prefetch early

    // ---- down GEMM: partial over this wave's K-quarter ----
    f32x4 acc = {0.f, 0.f, 0.f, 0.f};
#pragma unroll
    for (int s = 0; s < 8; ++s) {
      s16x8 a = *(const s16x8*)&xn[cur][c][kt * 256 + s * 32 + q * 8];
      acc = __builtin_amdgcn_mfma_f32_16x16x32_bf16(a, bdw[s], acc, 0, 0, 0);
    }
#pragma unroll
    for (int i = 0; i < 4; ++i)
      part[kt][ct][q * 4 + i][c] = acc[i];
    __syncthreads();

    // ---- K-reduce + bias + exact GELU -> gbf; wave role (rct=ct, rows rq*4..+4) ----
    {
      const int rq = w >> 2;    // == kt, reused as row-quad for reduction
      const int m  = rq * 4 + q;
      float h = part[0][ct][m][c] + part[1][ct][m][c]
              + part[2][ct][m][c] + part[3][ct][m][c] + dbr;
      float g = 0.5f * h * (1.0f + erff(h * 0.70710678118654752f));
      gbf[m][ct * 16 + c] = f2bf(g);
    }
    __syncthreads();

    // ---- up GEMM: wave owns H-cols [w*64, w*64+64); + bias + fp32 residual ----
    s16x8 a0 = *(const s16x8*)&gbf[c][q * 8];
    s16x8 a1 = *(const s16x8*)&gbf[c][32 + q * 8];
    const float* xres = x   + (rowbase + tile * RT) * HDIM;
    float*       ob   = out + (rowbase + tile * RT) * HDIM;
#pragma unroll
    for (int j = 0; j < 4; ++j) {
      f32x4 o4 = {0.f, 0.f, 0.f, 0.f};
      o4 = __builtin_amdgcn_mfma_f32_16x16x32_bf16(a0, buw[j][0], o4, 0, 0, 0);
      o4 = __builtin_amdgcn_mfma_f32_16x16x32_bf16(a1, buw[j][1], o4, 0, 0, 0);
      const int col = w * 64 + j * 16 + c;
#pragma unroll
      for (int i = 0; i < 4; ++i) {
        int ro = (q * 4 + i) * HDIM + col;
        ob[ro] = o4[i] + ubr[j] + xres[ro];       // residual from fp32 x (L1/L2-hot)
      }
    }

    // ---- LN for next tile into the other buffer ----
    stats_store(nxt);
    __syncthreads();
  }
}

extern "C" void kernel_launch(void* const* d_in, const int* in_sizes, int n_in,
                              void* d_out, int out_size, void* d_ws, size_t ws_size,
                              hipStream_t stream) {
  const float* x  = (const float*)d_in[0];
  const float* nw = (const float*)d_in[1];
  const float* nb = (const float*)d_in[2];
  const float* dw = (const float*)d_in[3];
  const float* db = (const float*)d_in[4];
  const float* uw = (const float*)d_in[5];
  const float* ub = (const float*)d_in[6];
  float* out = (float*)d_out;

  short* wsbf = (short*)d_ws;                 // 131072 shorts = 256 KB
  prep_weights<<<64, 256, 0, stream>>>(dw, uw, wsbf);

  const int rows = in_sizes[0] / HDIM;        // 32768
  const int grid = rows / (RT * NT);          // 256 persistent blocks (1/CU)
  adapter_fused<<<grid, 1024, 0, stream>>>(x, nw, nb, db, ub,
                                           wsbf, wsbf + 65536, out);
}